// Round 3
// baseline (231.813 us; speedup 1.0000x reference)
//
#include <hip/hip_runtime.h>
#include <math.h>

#define N_NODES 50000
#define D       64
#define N_EDGES 800000
#define N_HEAD  4

// ---------------------------------------------------------------------------
// row_ptr[r] = lower_bound(edge_row, r)  for r in [0, N_NODES], edge_row sorted
// ---------------------------------------------------------------------------
__global__ void rowptr_kernel(const int* __restrict__ edge_row,
                              int* __restrict__ row_ptr) {
    int r = blockIdx.x * blockDim.x + threadIdx.x;
    if (r > N_NODES) return;
    int lo = 0, hi = N_EDGES;
    while (lo < hi) {
        int mid = (lo + hi) >> 1;
        if (edge_row[mid] < r) lo = mid + 1; else hi = mid;
    }
    row_ptr[r] = lo;
}

// ---------------------------------------------------------------------------
// t[n][j] = elu( sum_k in[n][k] * W[j][k] + b[j] )
// lane j holds W[j][0..63] in 64 VGPRs; row data comes in as wave-uniform
// scalar loads (readfirstlane'd row index). No LDS.
// ---------------------------------------------------------------------------
__global__ __launch_bounds__(256) void linear_elu_kernel(
        const float* __restrict__ in,
        const float* __restrict__ W,   // [64][64] row-major, W[j][k]
        const float* __restrict__ b,   // [64]
        const int*  __restrict__ et,   // mask if et[n]==0 (head 0 only)
        float* __restrict__ t,
        int head0) {
    const int lane = threadIdx.x & 63;
    const int wid  = (blockIdx.x * blockDim.x + threadIdx.x) >> 6;
    const int nwav = (gridDim.x * blockDim.x) >> 6;

    float4 w4[16];
    {
        const float4* wp = (const float4*)(W + lane * D);
        #pragma unroll
        for (int i = 0; i < 16; ++i) w4[i] = wp[i];
    }
    const float* w = (const float*)w4;
    const float bj = b[lane];

    for (int row0 = wid; row0 < N_NODES; row0 += nwav) {
        const int row = __builtin_amdgcn_readfirstlane(row0);
        float acc = bj;
        if (!(head0 && et[row] == 0)) {
            const float* rp = in + (size_t)row * D;
            #pragma unroll
            for (int k = 0; k < D; ++k)
                acc = fmaf(rp[k], w[k], acc);
        }
        t[(size_t)row * D + lane] = (acc > 0.f) ? acc : expm1f(acc);
    }
}

// ---------------------------------------------------------------------------
// SpMM: h[r][:] = sum_{e in row r} val[e] * t[col[e]][:]
// One wave per row. Wave split into 4 groups of 16 lanes; group g handles
// edge e+g, each lane gathers a float4 (dims 4l..4l+3) -> one dwordx4 gather
// instruction covers 4 edges (1 KB). XOR-shuffle reduce merges the 4 group
// partials at the end. Main loop processes 16 edges/iter (4 gathers in flight).
// ---------------------------------------------------------------------------
__global__ __launch_bounds__(256) void spmm_kernel(
        const float* __restrict__ t,
        const int*   __restrict__ edge_col,
        const float* __restrict__ edge_val,
        const int*   __restrict__ row_ptr,
        float* __restrict__ h,
        float* __restrict__ out,
        int first_head, int write_h) {
    const int lane = threadIdx.x & 63;
    const int g    = lane >> 4;    // edge slot within quad
    const int l    = lane & 15;    // dim quad: dims [4l, 4l+4)
    int row0 = (blockIdx.x * blockDim.x + threadIdx.x) >> 6;
    if (row0 >= N_NODES) return;
    const int row = __builtin_amdgcn_readfirstlane(row0);

    const int e0 = row_ptr[row];
    const int e1 = row_ptr[row + 1];
    float4 acc = {0.f, 0.f, 0.f, 0.f};
    int e = e0;

    // main: 16 edges per iteration
    for (; e + 16 <= e1; e += 16) {
        int   c[4];
        float v[4];
        #pragma unroll
        for (int u = 0; u < 4; ++u) {
            c[u] = edge_col[e + 4 * u + g];
            v[u] = edge_val[e + 4 * u + g];
        }
        float4 t4[4];
        #pragma unroll
        for (int u = 0; u < 4; ++u)
            t4[u] = *(const float4*)(t + (size_t)c[u] * D + l * 4);
        #pragma unroll
        for (int u = 0; u < 4; ++u) {
            acc.x = fmaf(v[u], t4[u].x, acc.x);
            acc.y = fmaf(v[u], t4[u].y, acc.y);
            acc.z = fmaf(v[u], t4[u].z, acc.z);
            acc.w = fmaf(v[u], t4[u].w, acc.w);
        }
    }
    // remainder: 4 edges per iteration, masked
    for (; e < e1; e += 4) {
        const int ce = e + g;
        const bool ok = ce < e1;
        const int   c = ok ? edge_col[ce] : edge_col[e0];
        const float v = ok ? edge_val[ce] : 0.f;
        const float4 t4 = *(const float4*)(t + (size_t)c * D + l * 4);
        acc.x = fmaf(v, t4.x, acc.x);
        acc.y = fmaf(v, t4.y, acc.y);
        acc.z = fmaf(v, t4.z, acc.z);
        acc.w = fmaf(v, t4.w, acc.w);
    }

    // reduce across the 4 groups (lanes differing in bits 4,5)
    #pragma unroll
    for (int off = 16; off < 64; off <<= 1) {
        acc.x += __shfl_xor(acc.x, off, 64);
        acc.y += __shfl_xor(acc.y, off, 64);
        acc.z += __shfl_xor(acc.z, off, 64);
        acc.w += __shfl_xor(acc.w, off, 64);
    }

    if (g == 0) {
        const size_t base = (size_t)row * D + (size_t)l * 4;
        if (write_h) *(float4*)(h + base) = acc;
        if (first_head) {
            *(float4*)(out + base) = acc;
        } else {
            float4 o = *(const float4*)(out + base);
            o.x += acc.x; o.y += acc.y; o.z += acc.z; o.w += acc.w;
            *(float4*)(out + base) = o;
        }
    }
}

// ---------------------------------------------------------------------------
extern "C" void kernel_launch(void* const* d_in, const int* in_sizes, int n_in,
                              void* d_out, int out_size, void* d_ws, size_t ws_size,
                              hipStream_t stream) {
    const float* x        = (const float*)d_in[0];  // [N, 64]
    const float* edge_val = (const float*)d_in[1];  // [E]
    const float* W        = (const float*)d_in[2];  // [4, 64, 64]
    const float* b        = (const float*)d_in[3];  // [4, 64]
    const int* edge_row   = (const int*)d_in[4];    // sorted
    const int* edge_col   = (const int*)d_in[5];
    const int* event_type = (const int*)d_in[6];    // [N] (int32 on device)
    float* out = (float*)d_out;

    float* t       = (float*)d_ws;                    // [N*64]
    float* h       = t + (size_t)N_NODES * D;         // [N*64]
    int*   row_ptr = (int*)(h + (size_t)N_NODES * D); // [N+1]

    rowptr_kernel<<<(N_NODES + 256) / 256, 256, 0, stream>>>(edge_row, row_ptr);

    const float* cur = x;
    for (int i = 0; i < N_HEAD; ++i) {
        linear_elu_kernel<<<1024, 256, 0, stream>>>(
            cur, W + (size_t)i * D * D, b + (size_t)i * D,
            event_type, t, (i == 0) ? 1 : 0);
        spmm_kernel<<<(N_NODES * 64 + 255) / 256, 256, 0, stream>>>(
            t, edge_col, edge_val, row_ptr, h, out,
            (i == 0) ? 1 : 0, (i < N_HEAD - 1) ? 1 : 0);
        cur = h;
    }
}

// Round 4
// 206.330 us; speedup vs baseline: 1.1235x; 1.1235x over previous
//
#include <hip/hip_runtime.h>
#include <math.h>

#define N_NODES 50000
#define D       64
#define N_EDGES 800000
#define N_HEAD  4

typedef unsigned short ushort_t;

// bf16 <-> fp32 bit helpers (RNE on pack)
__device__ __forceinline__ float bf_lo(unsigned u) {
    return __uint_as_float(u << 16);
}
__device__ __forceinline__ float bf_hi(unsigned u) {
    return __uint_as_float(u & 0xffff0000u);
}
__device__ __forceinline__ ushort_t f2bf(float f) {
    unsigned u = __float_as_uint(f);
    u += 0x7fffu + ((u >> 16) & 1u);   // round-to-nearest-even
    return (ushort_t)(u >> 16);
}

// ---------------------------------------------------------------------------
// row_ptr[r] = lower_bound(edge_row, r)  for r in [0, N_NODES], edge_row sorted
// ---------------------------------------------------------------------------
__global__ void rowptr_kernel(const int* __restrict__ edge_row,
                              int* __restrict__ row_ptr) {
    int r = blockIdx.x * blockDim.x + threadIdx.x;
    if (r > N_NODES) return;
    int lo = 0, hi = N_EDGES;
    while (lo < hi) {
        int mid = (lo + hi) >> 1;
        if (edge_row[mid] < r) lo = mid + 1; else hi = mid;
    }
    row_ptr[r] = lo;
}

// ---------------------------------------------------------------------------
// t[n][j] = bf16( elu( sum_k in[n][k] * W[j][k] + b[j] ) )
// lane j holds W[j][0..63] in 64 VGPRs; row data comes in as wave-uniform
// scalar loads (readfirstlane'd row index). No LDS.
// ---------------------------------------------------------------------------
__global__ __launch_bounds__(256) void linear_elu_kernel(
        const float* __restrict__ in,
        const float* __restrict__ W,   // [64][64] row-major, W[j][k]
        const float* __restrict__ b,   // [64]
        const int*  __restrict__ et,   // mask if et[n]==0 (head 0 only)
        ushort_t* __restrict__ t,      // bf16 out
        int head0) {
    const int lane = threadIdx.x & 63;
    const int wid  = (blockIdx.x * blockDim.x + threadIdx.x) >> 6;
    const int nwav = (gridDim.x * blockDim.x) >> 6;

    float4 w4[16];
    {
        const float4* wp = (const float4*)(W + lane * D);
        #pragma unroll
        for (int i = 0; i < 16; ++i) w4[i] = wp[i];
    }
    const float* w = (const float*)w4;
    const float bj = b[lane];

    for (int row0 = wid; row0 < N_NODES; row0 += nwav) {
        const int row = __builtin_amdgcn_readfirstlane(row0);
        float acc = bj;
        if (!(head0 && et[row] == 0)) {
            const float* rp = in + (size_t)row * D;
            #pragma unroll
            for (int k = 0; k < D; ++k)
                acc = fmaf(rp[k], w[k], acc);
        }
        const float e = (acc > 0.f) ? acc : expm1f(acc);
        t[(size_t)row * D + lane] = f2bf(e);
    }
}

// ---------------------------------------------------------------------------
// SpMM: h[r][:] = sum_{e in row r} val[e] * t[col[e]][:]   (t is bf16)
// One wave per row. 4 groups of 16 lanes; group g handles edge e+g, each lane
// gathers a dwordx2 (4 bf16 = dims 4l..4l+3) -> one instr covers 4 edges.
// fp32 accumulate; XOR-shuffle merges the 4 group partials.
// ---------------------------------------------------------------------------
__global__ __launch_bounds__(256) void spmm_kernel(
        const ushort_t* __restrict__ t,  // bf16 [N][64]
        const int*   __restrict__ edge_col,
        const float* __restrict__ edge_val,
        const int*   __restrict__ row_ptr,
        float* __restrict__ h,
        float* __restrict__ out,
        int first_head, int write_h) {
    const int lane = threadIdx.x & 63;
    const int g    = lane >> 4;    // edge slot within quad
    const int l    = lane & 15;    // dim quad: dims [4l, 4l+4)
    int row0 = (blockIdx.x * blockDim.x + threadIdx.x) >> 6;
    if (row0 >= N_NODES) return;
    const int row = __builtin_amdgcn_readfirstlane(row0);

    const int e0 = row_ptr[row];
    const int e1 = row_ptr[row + 1];
    float4 acc = {0.f, 0.f, 0.f, 0.f};
    int e = e0;

    // main: 16 edges per iteration (4 gather instrs in flight)
    for (; e + 16 <= e1; e += 16) {
        int   c[4];
        float v[4];
        #pragma unroll
        for (int u = 0; u < 4; ++u) {
            c[u] = edge_col[e + 4 * u + g];
            v[u] = edge_val[e + 4 * u + g];
        }
        uint2 r2[4];
        #pragma unroll
        for (int u = 0; u < 4; ++u)
            r2[u] = *(const uint2*)(t + (size_t)c[u] * D + l * 4);
        #pragma unroll
        for (int u = 0; u < 4; ++u) {
            acc.x = fmaf(v[u], bf_lo(r2[u].x), acc.x);
            acc.y = fmaf(v[u], bf_hi(r2[u].x), acc.y);
            acc.z = fmaf(v[u], bf_lo(r2[u].y), acc.z);
            acc.w = fmaf(v[u], bf_hi(r2[u].y), acc.w);
        }
    }
    // remainder: 4 edges per iteration, masked
    for (; e < e1; e += 4) {
        const int ce = e + g;
        const bool ok = ce < e1;
        const int   c = ok ? edge_col[ce] : edge_col[e0];
        const float v = ok ? edge_val[ce] : 0.f;
        const uint2 r2 = *(const uint2*)(t + (size_t)c * D + l * 4);
        acc.x = fmaf(v, bf_lo(r2.x), acc.x);
        acc.y = fmaf(v, bf_hi(r2.x), acc.y);
        acc.z = fmaf(v, bf_lo(r2.y), acc.z);
        acc.w = fmaf(v, bf_hi(r2.y), acc.w);
    }

    // reduce across the 4 groups (lanes differing in bits 4,5)
    #pragma unroll
    for (int off = 16; off < 64; off <<= 1) {
        acc.x += __shfl_xor(acc.x, off, 64);
        acc.y += __shfl_xor(acc.y, off, 64);
        acc.z += __shfl_xor(acc.z, off, 64);
        acc.w += __shfl_xor(acc.w, off, 64);
    }

    if (g == 0) {
        const size_t base = (size_t)row * D + (size_t)l * 4;
        if (write_h) *(float4*)(h + base) = acc;
        if (first_head) {
            *(float4*)(out + base) = acc;
        } else {
            float4 o = *(const float4*)(out + base);
            o.x += acc.x; o.y += acc.y; o.z += acc.z; o.w += acc.w;
            *(float4*)(out + base) = o;
        }
    }
}

// ---------------------------------------------------------------------------
extern "C" void kernel_launch(void* const* d_in, const int* in_sizes, int n_in,
                              void* d_out, int out_size, void* d_ws, size_t ws_size,
                              hipStream_t stream) {
    const float* x        = (const float*)d_in[0];  // [N, 64]
    const float* edge_val = (const float*)d_in[1];  // [E]
    const float* W        = (const float*)d_in[2];  // [4, 64, 64]
    const float* b        = (const float*)d_in[3];  // [4, 64]
    const int* edge_row   = (const int*)d_in[4];    // sorted
    const int* edge_col   = (const int*)d_in[5];
    const int* event_type = (const int*)d_in[6];    // [N] (int32 on device)
    float* out = (float*)d_out;

    ushort_t* t    = (ushort_t*)d_ws;                      // bf16 [N*64]
    float* h       = (float*)(t + (size_t)N_NODES * D);    // fp32 [N*64]
    int*   row_ptr = (int*)(h + (size_t)N_NODES * D);      // [N+1]

    rowptr_kernel<<<(N_NODES + 256) / 256, 256, 0, stream>>>(edge_row, row_ptr);

    const float* cur = x;
    for (int i = 0; i < N_HEAD; ++i) {
        linear_elu_kernel<<<1024, 256, 0, stream>>>(
            cur, W + (size_t)i * D * D, b + (size_t)i * D,
            event_type, t, (i == 0) ? 1 : 0);
        spmm_kernel<<<(N_NODES * 64 + 255) / 256, 256, 0, stream>>>(
            t, edge_col, edge_val, row_ptr, h, out,
            (i == 0) ? 1 : 0, (i < N_HEAD - 1) ? 1 : 0);
        cur = h;
    }
}